// Round 2
// baseline (468.398 us; speedup 1.0000x reference)
//
#include <hip/hip_runtime.h>

// LieTransport: bilinear grid_sample (border pad, align_corners=False) of
// h_prev [B,C,H,W,R] with grid = base_grid - flow*dt, flow shared across C,R.
// Output layout identical to input: [B, C, H, W, R], fp32.
//
// Round 4: same as Round 3 (latency pipeline) with the compile fix:
// __builtin_nontemporal_store needs a native clang vector type, not HIP's
// float4 class -> cast through ext_vector_type(4) float.
//
// Rationale recap: rocprof showed HBM traffic already ideal (FETCH 269 MB,
// WRITE 268 MB) but only 42% of achievable BW, VALUBusy 30% -- latency/issue
// bound. 8192 blocks x 8 pixels along x; flow for all 8 pixels loaded once as
// 4x float4; fully-unrolled 2-buffer software pipeline keeps pixel k+1's four
// gathers in flight while pixel k blends. Nontemporal stores keep the 268 MB
// write stream from evicting the gather-reuse window in L2. XCD slab swizzle
// retained (contiguous slab per XCD, 8 | 8192).

constexpr int B = 4, C = 16, H = 128, W = 128, R = 64;
constexpr int R4 = R / 4;           // float4 groups per pixel-channel
constexpr int NPIX = B * H * W;     // 65536
constexpr int NP = 8;               // pixels per block (along x; 8 | W)
constexpr int NGRP = NPIX / NP;     // 8192 blocks
constexpr int NXCD = 8;
constexpr int GSLAB = NGRP / NXCD;  // 1024 groups per XCD slab

using vfloat4 = __attribute__((ext_vector_type(4))) float;

struct Px { int i00, i01, i10, i11; float wx, wy; };

__global__ __launch_bounds__(256) void lie_transport_kernel(
    const float* __restrict__ h,     // [B,C,H,W,R]
    const float* __restrict__ flow,  // [B,2,H,W]
    const float* __restrict__ dt,    // [B]
    float* __restrict__ out)         // [B,C,H,W,R]
{
    // XCD-aware swizzle: hardware assigns workgroup -> XCD as blockIdx % 8.
    const int raw  = blockIdx.x;
    const int grp  = (raw & (NXCD - 1)) * GSLAB + (raw >> 3);
    const int pix0 = grp * NP;

    const int b  = pix0 >> 14;       // / (H*W)
    const int yx = pix0 & 16383;
    const int y  = yx >> 7;
    const int xb = yx & 127;         // multiple of NP, so xb+7 <= 127

    const int t  = threadIdx.x;
    const int c  = t >> 4;
    const int r4 = t & 15;

    const float4* __restrict__ h4 = (const float4*)h;
    float4* __restrict__ o4 = (float4*)out;
    const float4* __restrict__ f4 = (const float4*)flow;

    // ---- flow + dt for all 8 pixels, loaded once (block-uniform) ----
    const float dtb = dt[b];
    const int fbase = (b * 2 * H + y) * W + xb;          // xb % 4 == 0
    const float4 fxa = f4[(fbase >> 2) + 0];
    const float4 fxb = f4[(fbase >> 2) + 1];
    const float4 fya = f4[((fbase + H * W) >> 2) + 0];
    const float4 fyb = f4[((fbase + H * W) >> 2) + 1];

    const float fxv[NP] = {fxa.x, fxa.y, fxa.z, fxa.w, fxb.x, fxb.y, fxb.z, fxb.w};
    const float fyv[NP] = {fya.x, fya.y, fya.z, fya.w, fyb.x, fyb.y, fyb.z, fyb.w};

    const int planeBase = (b * C + c) * H;
    const int rowOff = planeBase * W * R4 + r4;          // add (y*W+x)*R4 per tap
    const float gy0 = -1.0f + 2.0f * (float)y / (float)(H - 1);

    // Per-pixel sampling coords (same arithmetic as the verified Round-2 kernel)
    auto coords = [&](int k) -> Px {
        const float gx  = (-1.0f + 2.0f * (float)(xb + k) / (float)(W - 1)) - fxv[k] * dtb;
        const float gyv = gy0 - fyv[k] * dtb;
        float xs = ((gx  + 1.0f) * (float)W - 1.0f) * 0.5f;
        float ys = ((gyv + 1.0f) * (float)H - 1.0f) * 0.5f;
        xs = fminf(fmaxf(xs, 0.0f), (float)(W - 1));
        ys = fminf(fmaxf(ys, 0.0f), (float)(H - 1));
        const float x0f = floorf(xs);
        const float y0f = floorf(ys);
        Px p;
        p.wx = xs - x0f;
        p.wy = ys - y0f;
        const int x0  = (int)x0f;
        const int y0i = (int)y0f;
        const int x1  = min(x0 + 1, W - 1);
        const int y1  = min(y0i + 1, H - 1);
        p.i00 = rowOff + (y0i * W + x0) * R4;
        p.i01 = rowOff + (y0i * W + x1) * R4;
        p.i10 = rowOff + (y1  * W + x0) * R4;
        p.i11 = rowOff + (y1  * W + x1) * R4;
        return p;
    };

    auto blend = [&](const Px& p, const float4& v00, const float4& v01,
                     const float4& v10, const float4& v11) -> float4 {
        const float w1mx = 1.0f - p.wx;
        const float w1my = 1.0f - p.wy;
        float4 r;
        r.x = (v00.x * w1mx + v01.x * p.wx) * w1my + (v10.x * w1mx + v11.x * p.wx) * p.wy;
        r.y = (v00.y * w1mx + v01.y * p.wx) * w1my + (v10.y * w1mx + v11.y * p.wx) * p.wy;
        r.z = (v00.z * w1mx + v01.z * p.wx) * w1my + (v10.z * w1mx + v11.z * p.wx) * p.wy;
        r.w = (v00.w * w1mx + v01.w * p.wx) * w1my + (v10.w * w1mx + v11.w * p.wx) * p.wy;
        return r;
    };

    auto store_nt = [&](const float4& v, float4* dst) {
        vfloat4 nv;
        nv.x = v.x; nv.y = v.y; nv.z = v.z; nv.w = v.w;
        __builtin_nontemporal_store(nv, (vfloat4*)dst);
    };

    const int obase = ((planeBase + y) * W + xb) * R4 + r4;

    // ---- software pipeline: 2 buffers, fully unrolled (all indices static) ----
    Px pA = coords(0);
    float4 a00 = h4[pA.i00], a01 = h4[pA.i01], a10 = h4[pA.i10], a11 = h4[pA.i11];
    Px pB = coords(1);
    float4 b00 = h4[pB.i00], b01 = h4[pB.i01], b10 = h4[pB.i10], b11 = h4[pB.i11];

    #pragma unroll
    for (int k = 0; k < NP; k += 2) {
        const float4 rA = blend(pA, a00, a01, a10, a11);
        store_nt(rA, &o4[obase + k * R4]);
        if (k + 2 < NP) {
            pA = coords(k + 2);
            a00 = h4[pA.i00]; a01 = h4[pA.i01]; a10 = h4[pA.i10]; a11 = h4[pA.i11];
        }
        const float4 rB = blend(pB, b00, b01, b10, b11);
        store_nt(rB, &o4[obase + (k + 1) * R4]);
        if (k + 3 < NP) {
            pB = coords(k + 3);
            b00 = h4[pB.i00]; b01 = h4[pB.i01]; b10 = h4[pB.i10]; b11 = h4[pB.i11];
        }
    }
}

extern "C" void kernel_launch(void* const* d_in, const int* in_sizes, int n_in,
                              void* d_out, int out_size, void* d_ws, size_t ws_size,
                              hipStream_t stream) {
    const float* h_prev = (const float*)d_in[0]; // [4,16,128,128,64]
    const float* flow   = (const float*)d_in[1]; // [4,2,128,128]
    const float* dt     = (const float*)d_in[2]; // [4]
    float* out = (float*)d_out;

    lie_transport_kernel<<<NGRP, 256, 0, stream>>>(h_prev, flow, dt, out);
}